// Round 3
// baseline (2786.470 us; speedup 1.0000x reference)
//
#include <hip/hip_runtime.h>
#include <stdint.h>

typedef unsigned short u16;
typedef __attribute__((ext_vector_type(8))) short s16x8;
typedef __attribute__((ext_vector_type(4))) float f32x4;

#define DEV static __device__ __forceinline__

// ---------- helpers ----------
DEV u16 f2bf(float f){
  uint32_t u = __builtin_bit_cast(uint32_t, f);
  u += 0x7fffu + ((u >> 16) & 1u);          // RNE
  return (u16)(u >> 16);
}
DEV float bf2f(u16 h){
  uint32_t u = ((uint32_t)h) << 16;
  return __builtin_bit_cast(float, u);
}
DEV void gload_lds16(const void* g, void* l){
  __builtin_amdgcn_global_load_lds((const __attribute__((address_space(1))) void*)g,
                                   (__attribute__((address_space(3))) void*)l, 16, 0, 0);
}

// ---------- constants ----------
#define BB 2
#define SS 1024
#define DD 1024
#define HH 16
#define HDD 64
#define NBLK 8
#define DFF 4096
#define VV 32000
#define MM 2048   // B*S

// ---------- weight conversion ----------
__global__ void convert_f2b(const float* __restrict__ src, u16* __restrict__ dst, int n4){
  int i = blockIdx.x * blockDim.x + threadIdx.x;
  int stride = gridDim.x * blockDim.x;
  for (; i < n4; i += stride){
    float4 v = ((const float4*)src)[i];
    ushort4 o;
    o.x = f2bf(v.x); o.y = f2bf(v.y); o.z = f2bf(v.z); o.w = f2bf(v.w);
    ((ushort4*)dst)[i] = o;
  }
}

// pack wq/wk/wv -> [NBLK][3][1024][1024] bf16
__global__ void convert_qkv(const float* __restrict__ wq, const float* __restrict__ wk,
                            const float* __restrict__ wv, u16* __restrict__ dst, int n4){
  int i = blockIdx.x * blockDim.x + threadIdx.x;
  int stride = gridDim.x * blockDim.x;
  const int PER_L = 3 * 1048576;
  for (; i < n4; i += stride){
    int e = i * 4;
    int layer = e / PER_L;
    int rem = e - layer * PER_L;
    int which = rem >> 20;
    int off = rem & 1048575;
    const float* src = (which == 0 ? wq : (which == 1 ? wk : wv)) + (size_t)layer * 1048576 + off;
    float4 v = *(const float4*)src;
    ushort4 o;
    o.x = f2bf(v.x); o.y = f2bf(v.y); o.z = f2bf(v.z); o.w = f2bf(v.w);
    ((ushort4*)dst)[i] = o;
  }
}

// ---------- embedding ----------
__global__ void embed_k(const int* __restrict__ ctx, const float* __restrict__ tok,
                        const float* __restrict__ pos, float* __restrict__ x){
  int row = blockIdx.x;              // b*S + s
  int s = row & (SS - 1);
  int t = threadIdx.x;               // 256 threads * 4 = 1024
  int tk = ctx[row];
  float4 a = ((const float4*)(tok + (size_t)tk * DD))[t];
  float4 p = ((const float4*)(pos + (size_t)s * DD))[t];
  a.x += p.x; a.y += p.y; a.z += p.z; a.w += p.w;
  ((float4*)(x + (size_t)row * DD))[t] = a;
}

// ---------- layernorm (f32 in -> bf16 out) ----------
__global__ void layernorm_k(const float* __restrict__ x, const float* __restrict__ w,
                            const float* __restrict__ b, u16* __restrict__ out){
  int row = blockIdx.x;
  int t = threadIdx.x;
  float4 v = ((const float4*)(x + (size_t)row * DD))[t];
  float s = v.x + v.y + v.z + v.w;
  float ss = v.x*v.x + v.y*v.y + v.z*v.z + v.w*v.w;
  #pragma unroll
  for (int m = 1; m < 64; m <<= 1){
    s  += __shfl_xor(s,  m, 64);
    ss += __shfl_xor(ss, m, 64);
  }
  __shared__ float rs[4], rss[4];
  int wv_ = t >> 6;
  if ((t & 63) == 0){ rs[wv_] = s; rss[wv_] = ss; }
  __syncthreads();
  s  = rs[0] + rs[1] + rs[2] + rs[3];
  ss = rss[0] + rss[1] + rss[2] + rss[3];
  float mu = s * (1.f/1024.f);
  float var = ss * (1.f/1024.f) - mu*mu;
  float inv = rsqrtf(var + 1e-5f);
  float4 wv4 = ((const float4*)w)[t];
  float4 bv4 = ((const float4*)b)[t];
  ushort4 o;
  o.x = f2bf((v.x - mu)*inv*wv4.x + bv4.x);
  o.y = f2bf((v.y - mu)*inv*wv4.y + bv4.y);
  o.z = f2bf((v.z - mu)*inv*wv4.z + bv4.z);
  o.w = f2bf((v.w - mu)*inv*wv4.w + bv4.w);
  ((ushort4*)(out + (size_t)row * DD))[t] = o;
}

// ---------- GEMM: C[M,N] = A[M,K] @ B[N,K]^T (+bias, relu, residual) ----------
// OUT_MODE 0: write bf16 Cb; 1: Cf += ; 2: Cf =
template<int OUT_MODE, bool BIAS, bool RELU>
__global__ __launch_bounds__(256, 2) void gemm_bt(
    const u16* __restrict__ A, const u16* __restrict__ B,
    const float* __restrict__ bias, float* __restrict__ Cf, u16* __restrict__ Cb,
    int N, int K, int MT)
{
  __shared__ __align__(16) u16 As[128*32];
  __shared__ __align__(16) u16 Bs[128*32];
  const int t = threadIdx.x;
  const int w = t >> 6, lane = t & 63;
  const int l15 = lane & 15, l4 = lane >> 4;
  const int bid = blockIdx.x;
  const int mt = bid % MT, nt = bid / MT;
  const int wr = (w >> 1) * 64, wc = (w & 1) * 64;

  f32x4 acc[4][4];
  #pragma unroll
  for (int i = 0; i < 4; i++)
    #pragma unroll
    for (int j = 0; j < 4; j++) acc[i][j] = (f32x4){0.f,0.f,0.f,0.f};

  const int colb = (t & 3) * 8;
  const u16* Ag0 = A + ((size_t)mt*128 + (t>>2)) * K + colb;
  const u16* Ag1 = Ag0 + (size_t)64 * K;
  const u16* Bg0 = B + ((size_t)nt*128 + (t>>2)) * K + colb;
  const u16* Bg1 = Bg0 + (size_t)64 * K;
  u16* AsW0 = As + (w << 9);         // wave-uniform LDS bases
  u16* AsW1 = As + 2048 + (w << 9);
  u16* BsW0 = Bs + (w << 9);
  u16* BsW1 = Bs + 2048 + (w << 9);

  for (int k0 = 0; k0 < K; k0 += 32){
    gload_lds16(Ag0 + k0, AsW0);
    gload_lds16(Ag1 + k0, AsW1);
    gload_lds16(Bg0 + k0, BsW0);
    gload_lds16(Bg1 + k0, BsW1);
    __syncthreads();
    s16x8 af[4], bfr[4];
    #pragma unroll
    for (int mi = 0; mi < 4; mi++)
      af[mi] = *(const s16x8*)(As + (wr + mi*16 + l15)*32 + l4*8);
    #pragma unroll
    for (int ni = 0; ni < 4; ni++)
      bfr[ni] = *(const s16x8*)(Bs + (wc + ni*16 + l15)*32 + l4*8);
    #pragma unroll
    for (int mi = 0; mi < 4; mi++)
      #pragma unroll
      for (int ni = 0; ni < 4; ni++)
        acc[mi][ni] = __builtin_amdgcn_mfma_f32_16x16x32_bf16(af[mi], bfr[ni], acc[mi][ni], 0, 0, 0);
    __syncthreads();
  }

  #pragma unroll
  for (int mi = 0; mi < 4; mi++){
    #pragma unroll
    for (int ni = 0; ni < 4; ni++){
      #pragma unroll
      for (int r = 0; r < 4; r++){
        size_t row = (size_t)mt*128 + wr + mi*16 + l4*4 + r;
        int col = nt*128 + wc + ni*16 + l15;
        float v = acc[mi][ni][r];
        if (BIAS) v += bias[col];
        if (RELU) v = fmaxf(v, 0.f);
        if (OUT_MODE == 0)      Cb[row * N + col] = f2bf(v);
        else if (OUT_MODE == 1) Cf[row * N + col] += v;
        else                    Cf[row * N + col] = v;
      }
    }
  }
}

// ---------- transpose V slice of qkv -> vt[bh][64][1024] ----------
__global__ void transpose_v(const u16* __restrict__ qkv, u16* __restrict__ vt){
  __shared__ u16 tile[64][72];
  const int bh = blockIdx.y;
  const int b = bh >> 4, h = bh & 15;
  const int s0 = blockIdx.x * 64;
  const int t = threadIdx.x;
  const int sl = t >> 2, c = (t & 3) * 16;
  const u16* src = qkv + (size_t)(b*SS + s0 + sl) * 3072 + 2048 + h*64 + c;
  s16x8 v0 = *(const s16x8*)src;
  s16x8 v1 = *(const s16x8*)(src + 8);
  #pragma unroll
  for (int j = 0; j < 8; j++){ tile[sl][c+j] = (u16)v0[j]; tile[sl][c+8+j] = (u16)v1[j]; }
  __syncthreads();
  const int dl = t >> 2, sc = (t & 3) * 16;
  u16* dst = vt + (size_t)(bh*64 + dl) * SS + s0 + sc;
  u16 tmp[16];
  #pragma unroll
  for (int j = 0; j < 16; j++) tmp[j] = tile[sc + j][dl];
  #pragma unroll
  for (int j = 0; j < 16; j++) dst[j] = tmp[j];
}

// ---------- flash attention (causal), x += attn_out ----------
__global__ __launch_bounds__(256, 2) void attn_k(
    const u16* __restrict__ qkv, const u16* __restrict__ vt, float* __restrict__ x)
{
  __shared__ __align__(16) u16 P[4][32][72];
  const int t = threadIdx.x, w = t >> 6, lane = t & 63;
  const int l15 = lane & 15, l4 = lane >> 4;
  const int qt = blockIdx.x, bh = blockIdx.y;
  const int b = bh >> 4, h = bh & 15;
  const int wq0 = qt*128 + w*32;          // this wave's first q row (within S)

  s16x8 aq[2][2];
  #pragma unroll
  for (int qs = 0; qs < 2; qs++)
    #pragma unroll
    for (int ks = 0; ks < 2; ks++)
      aq[qs][ks] = *(const s16x8*)(qkv + (size_t)(b*SS + wq0 + qs*16 + l15)*3072 + h*64 + ks*32 + l4*8);

  float ms[2][4], ls[2][4];
  f32x4 o[2][4];
  #pragma unroll
  for (int qs = 0; qs < 2; qs++)
    #pragma unroll
    for (int r = 0; r < 4; r++){ ms[qs][r] = -1e30f; ls[qs][r] = 0.f; }
  #pragma unroll
  for (int qs = 0; qs < 2; qs++)
    #pragma unroll
    for (int hs = 0; hs < 4; hs++) o[qs][hs] = (f32x4){0.f,0.f,0.f,0.f};

  const int nkv = (wq0 + 31)/64 + 1;
  for (int kv = 0; kv < nkv; kv++){
    const int kv0 = kv * 64;
    f32x4 s[2][4];
    #pragma unroll
    for (int qs = 0; qs < 2; qs++)
      #pragma unroll
      for (int ns = 0; ns < 4; ns++) s[qs][ns] = (f32x4){0.f,0.f,0.f,0.f};

    #pragma unroll
    for (int ks = 0; ks < 2; ks++){
      s16x8 bk[4];
      #pragma unroll
      for (int ns = 0; ns < 4; ns++)
        bk[ns] = *(const s16x8*)(qkv + (size_t)(b*SS + kv0 + ns*16 + l15)*3072 + 1024 + h*64 + ks*32 + l4*8);
      #pragma unroll
      for (int qs = 0; qs < 2; qs++)
        #pragma unroll
        for (int ns = 0; ns < 4; ns++)
          s[qs][ns] = __builtin_amdgcn_mfma_f32_16x16x32_bf16(aq[qs][ks], bk[ns], s[qs][ns], 0, 0, 0);
    }

    float rm[2][4];
    #pragma unroll
    for (int qs = 0; qs < 2; qs++)
      #pragma unroll
      for (int r = 0; r < 4; r++) rm[qs][r] = -1e30f;
    #pragma unroll
    for (int qs = 0; qs < 2; qs++)
      #pragma unroll
      for (int ns = 0; ns < 4; ns++)
        #pragma unroll
        for (int r = 0; r < 4; r++){
          int qrow = wq0 + qs*16 + l4*4 + r;
          int kcol = kv0 + ns*16 + l15;
          float v = s[qs][ns][r] * 0.125f;
          v = (kcol <= qrow) ? v : -1e30f;
          s[qs][ns][r] = v;
          rm[qs][r] = fmaxf(rm[qs][r], v);
        }
    #pragma unroll
    for (int qs = 0; qs < 2; qs++)
      #pragma unroll
      for (int r = 0; r < 4; r++)
        #pragma unroll
        for (int m = 1; m < 16; m <<= 1)
          rm[qs][r] = fmaxf(rm[qs][r], __shfl_xor(rm[qs][r], m, 64));

    float corr[2][4];
    #pragma unroll
    for (int qs = 0; qs < 2; qs++)
      #pragma unroll
      for (int r = 0; r < 4; r++){
        float mn = fmaxf(ms[qs][r], rm[qs][r]);
        corr[qs][r] = __expf(ms[qs][r] - mn);
        ms[qs][r] = mn;
      }
    float rsum[2][4];
    #pragma unroll
    for (int qs = 0; qs < 2; qs++)
      #pragma unroll
      for (int r = 0; r < 4; r++) rsum[qs][r] = 0.f;
    #pragma unroll
    for (int qs = 0; qs < 2; qs++)
      #pragma unroll
      for (int ns = 0; ns < 4; ns++)
        #pragma unroll
        for (int r = 0; r < 4; r++){
          float p = __expf(s[qs][ns][r] - ms[qs][r]);
          s[qs][ns][r] = p;
          rsum[qs][r] += p;
        }
    #pragma unroll
    for (int qs = 0; qs < 2; qs++)
      #pragma unroll
      for (int r = 0; r < 4; r++){
        #pragma unroll
        for (int m = 1; m < 16; m <<= 1)
          rsum[qs][r] += __shfl_xor(rsum[qs][r], m, 64);
        ls[qs][r] = ls[qs][r] * corr[qs][r] + rsum[qs][r];
      }
    #pragma unroll
    for (int qs = 0; qs < 2; qs++)
      #pragma unroll
      for (int hs = 0; hs < 4; hs++)
        #pragma unroll
        for (int r = 0; r < 4; r++) o[qs][hs][r] *= corr[qs][r];

    // P -> LDS (per-wave region), then read transposed A-fragments
    #pragma unroll
    for (int qs = 0; qs < 2; qs++)
      #pragma unroll
      for (int ns = 0; ns < 4; ns++)
        #pragma unroll
        for (int r = 0; r < 4; r++)
          P[w][qs*16 + l4*4 + r][ns*16 + l15] = f2bf(s[qs][ns][r]);
    asm volatile("s_waitcnt lgkmcnt(0)" ::: "memory");
    __builtin_amdgcn_sched_barrier(0);

    s16x8 ap[2][2];
    #pragma unroll
    for (int qs = 0; qs < 2; qs++)
      #pragma unroll
      for (int k2 = 0; k2 < 2; k2++)
        ap[qs][k2] = *(const s16x8*)(&P[w][qs*16 + l15][k2*32 + l4*8]);

    #pragma unroll
    for (int hs = 0; hs < 4; hs++){
      const u16* vrow = vt + (size_t)(bh*64 + hs*16 + l15) * SS + kv0 + l4*8;
      s16x8 bv0 = *(const s16x8*)(vrow);
      s16x8 bv1 = *(const s16x8*)(vrow + 32);
      #pragma unroll
      for (int qs = 0; qs < 2; qs++){
        o[qs][hs] = __builtin_amdgcn_mfma_f32_16x16x32_bf16(ap[qs][0], bv0, o[qs][hs], 0, 0, 0);
        o[qs][hs] = __builtin_amdgcn_mfma_f32_16x16x32_bf16(ap[qs][1], bv1, o[qs][hs], 0, 0, 0);
      }
    }
  }

  #pragma unroll
  for (int qs = 0; qs < 2; qs++)
    #pragma unroll
    for (int hs = 0; hs < 4; hs++)
      #pragma unroll
      for (int r = 0; r < 4; r++){
        size_t row = (size_t)b*SS + wq0 + qs*16 + l4*4 + r;
        int col = h*64 + hs*16 + l15;
        x[row * DD + col] += o[qs][hs][r] / ls[qs][r];
      }
}

// ---------- host ----------
extern "C" void kernel_launch(void* const* d_in, const int* in_sizes, int n_in,
                              void* d_out, int out_size, void* d_ws, size_t ws_size,
                              hipStream_t stream) {
  const int*   ctx  = (const int*)  d_in[0];
  const float* tok  = (const float*)d_in[1];
  const float* pos  = (const float*)d_in[2];
  const float* wq   = (const float*)d_in[3];
  const float* wk   = (const float*)d_in[4];
  const float* wv   = (const float*)d_in[5];
  const float* upw  = (const float*)d_in[6];
  const float* upb  = (const float*)d_in[7];
  const float* dnw  = (const float*)d_in[8];
  const float* dnb  = (const float*)d_in[9];
  const float* ln1w = (const float*)d_in[10];
  const float* ln1b = (const float*)d_in[11];
  const float* ln2w = (const float*)d_in[12];
  const float* ln2b = (const float*)d_in[13];
  const float* lnfw = (const float*)d_in[14];
  const float* lnfb = (const float*)d_in[15];
  const float* outw = (const float*)d_in[16];
  const float* outb = (const float*)d_in[17];
  float* out = (float*)d_out;

  char* p = (char*)d_ws;
  auto alloc = [&](size_t bytes){ void* r = (void*)p; p += (bytes + 255) & ~(size_t)255; return r; };
  u16*   wqkvB = (u16*)  alloc((size_t)NBLK*3*1024*1024*2);
  u16*   wupB  = (u16*)  alloc((size_t)NBLK*DFF*DD*2);
  u16*   wdnB  = (u16*)  alloc((size_t)NBLK*DD*DFF*2);
  u16*   woutB = (u16*)  alloc((size_t)VV*DD*2);
  float* x     = (float*)alloc((size_t)MM*DD*4);
  u16*   xn    = (u16*)  alloc((size_t)MM*DD*2);
  u16*   qkvB  = (u16*)  alloc((size_t)MM*3072*2);
  u16*   vtB   = (u16*)  alloc((size_t)BB*HH*HDD*SS*2);
  u16*   hhB   = (u16*)  alloc((size_t)MM*DFF*2);

  convert_qkv<<<2048, 256, 0, stream>>>(wq, wk, wv, wqkvB, NBLK*3*1048576/4);
  convert_f2b<<<2048, 256, 0, stream>>>(upw,  wupB,  NBLK*DFF*DD/4);
  convert_f2b<<<2048, 256, 0, stream>>>(dnw,  wdnB,  NBLK*DD*DFF/4);
  convert_f2b<<<2048, 256, 0, stream>>>(outw, woutB, VV*DD/4);

  embed_k<<<MM, 256, 0, stream>>>(ctx, tok, pos, x);

  for (int i = 0; i < NBLK; i++){
    layernorm_k<<<MM, 256, 0, stream>>>(x, ln1w + i*DD, ln1b + i*DD, xn);
    gemm_bt<0,false,false><<<24*16, 256, 0, stream>>>(xn, wqkvB + (size_t)i*3*1024*1024,
                                                      nullptr, nullptr, qkvB, 3072, 1024, 16);
    transpose_v<<<dim3(16, 32), 256, 0, stream>>>(qkvB, vtB);
    attn_k<<<dim3(8, 32), 256, 0, stream>>>(qkvB, vtB, x);
    layernorm_k<<<MM, 256, 0, stream>>>(x, ln2w + i*DD, ln2b + i*DD, xn);
    gemm_bt<0,true,true><<<32*16, 256, 0, stream>>>(xn, wupB + (size_t)i*DFF*DD,
                                                    upb + i*DFF, nullptr, hhB, 4096, 1024, 16);
    gemm_bt<1,true,false><<<8*16, 256, 0, stream>>>(hhB, wdnB + (size_t)i*DD*DFF,
                                                    dnb + i*DD, x, nullptr, 1024, 4096, 16);
  }

  layernorm_k<<<MM, 256, 0, stream>>>(x, lnfw, lnfb, xn);
  gemm_bt<2,true,false><<<250*16, 256, 0, stream>>>(xn, woutB, outb, out, nullptr, 32000, 1024, 16);
}